// Round 2
// baseline (169.277 us; speedup 1.0000x reference)
//
#include <hip/hip_runtime.h>
#include <cstdint>
#include <cstddef>

// ELBO loss: top-256 of gamma -> M = I + D^1/2 Rkk D^1/2 (SPD, packed lower
// 8x8-blocks in LDS) -> blocked Cholesky (NB=32) with MFMA split-bf16 SYRK
// -> loss = sum(log Lii) + 0.5*(z.S - (L^-1 t1).(L^-1 t2)) + KL
//
// Packed layout: element (i,j), j<=i (plus intra-block upper of diag 8x8
// blocks, kept symmetric-consistent): blk(I=i>>3, J=j>>3) at
// (I*(I+1)/2+J)*68 + (i&7)*8 + (j&7).  68-float block stride skews banks.

#define BLK_STRIDE 68
#define PK_TOTAL (528 * BLK_STRIDE)  // 35904 floats = 143616 B

typedef __attribute__((ext_vector_type(8))) short short8_t;
typedef __attribute__((ext_vector_type(16))) float f32x16;

__device__ __forceinline__ int blk_off(int I, int J) {
  return (((I * (I + 1)) >> 1) + J) * BLK_STRIDE;
}

__device__ __forceinline__ float bcast_lane(float v, int lane) {
  return __int_as_float(__builtin_amdgcn_readlane(__float_as_int(v), lane));
}

// RNE split: f ~= hi + lo in bf16 bit-patterns (as shorts)
__device__ __forceinline__ void split_bf16(float f, short& h, short& l) {
  unsigned u = __float_as_uint(f);
  unsigned hr = (u + 0x7FFFu + ((u >> 16) & 1u)) >> 16;
  h = (short)hr;
  float hf = __uint_as_float(hr << 16);
  float lf = f - hf;
  unsigned u2 = __float_as_uint(lf);
  l = (short)((u2 + 0x7FFFu + ((u2 >> 16) & 1u)) >> 16);
}

__device__ __forceinline__ void frag_from_row(const float* Mp, int row_abs,
                                              int kb, short8_t& hi,
                                              short8_t& lo) {
  int o = blk_off(row_abs >> 3, kb >> 3) + (row_abs & 7) * 8;
  float4 v0 = *(const float4*)&Mp[o];
  float4 v1 = *(const float4*)&Mp[o + 4];
  float f[8] = {v0.x, v0.y, v0.z, v0.w, v1.x, v1.y, v1.z, v1.w};
  #pragma unroll
  for (int i = 0; i < 8; ++i) {
    short h, l;
    split_bf16(f[i], h, l);
    hi[i] = h;
    lo[i] = l;
  }
}

// ---------------- K1: exact top-256 select by rank + per-selected scalars ---
__global__ __launch_bounds__(256) void k_topk(
    const float* __restrict__ gamma, const float* __restrict__ sigma2,
    const float* __restrict__ z, const float* __restrict__ p,
    const float* __restrict__ pq, const int* __restrict__ Nptr,
    int* __restrict__ ind, float* __restrict__ sqv,
    float* __restrict__ t1, float* __restrict__ klt) {
  __shared__ __align__(16) float g[8 * 1032];
  int t = threadIdx.x;
  const float4* ga4 = (const float4*)gamma;
  #pragma unroll
  for (int m = 0; m < 8; ++m) {
    int i = 4 * (t + m * 256);
    float4 v = ga4[t + m * 256];
    *(float4*)&g[i + 8 * (i >> 10)] = v;
  }
  __syncthreads();
  int e = blockIdx.x * 32 + (t >> 3);
  int chunk = t & 7;
  float ge = g[e + 8 * (e >> 10)];
  const float4* g4 = (const float4*)g;
  int i4base = chunk * 258;
  int jbase = chunk * 1024;
  int cnt = 0;
  for (int it = 0; it < 256; ++it) {
    float4 v = g4[i4base + it];
    int j = jbase + 4 * it;
    cnt += (v.x > ge || (v.x == ge && (j + 0) < e)) ? 1 : 0;
    cnt += (v.y > ge || (v.y == ge && (j + 1) < e)) ? 1 : 0;
    cnt += (v.z > ge || (v.z == ge && (j + 2) < e)) ? 1 : 0;
    cnt += (v.w > ge || (v.w == ge && (j + 3) < e)) ? 1 : 0;
  }
  cnt += __shfl_xor(cnt, 1);
  cnt += __shfl_xor(cnt, 2);
  cnt += __shfl_xor(cnt, 4);
  if (chunk == 0 && cnt < 256) {
    float u = ge;
    float mask = (u > 0.01f) ? 1.0f : 0.0f;
    float fN = (float)Nptr[0];
    float vals = fN * sigma2[e] * u * mask;
    float sq = sqrtf(vals);
    ind[cnt] = e;
    sqv[cnt] = sq;
    t1[cnt] = sq * z[e];
    float x1 = p[e], x2 = pq[e];
    klt[cnt] = mask * (x2 * (logf(x2) - logf(x1)) +
                       (1.0f - x2) * (logf(1.0f - x2) - logf(1.0f - x1)));
  }
}

// ---------------- K2: VS = Rk.S, build packed M, and z.S --------------------
__global__ __launch_bounds__(256) void k_vs(
    const float* __restrict__ R, const float* __restrict__ S,
    const float* __restrict__ z, const int* __restrict__ ind,
    const float* __restrict__ sqv, float* __restrict__ Mp_g,
    float* __restrict__ t2, float* __restrict__ zS) {
  __shared__ __align__(16) float row[8192];
  __shared__ float red[4];
  int t = threadIdx.x;
  int b = blockIdx.x;
  if (b < 256) {
    int ridx = ind[b];
    const float4* Rr = (const float4*)(R + (size_t)ridx * 8192);
    const float4* S4 = (const float4*)S;
    float4* row4 = (float4*)row;
    float acc = 0.0f;
    #pragma unroll
    for (int m = 0; m < 8; ++m) {
      float4 v = Rr[t + m * 256];
      row4[t + m * 256] = v;
      float4 s = S4[t + m * 256];
      acc += v.x * s.x + v.y * s.y + v.z * s.z + v.w * s.w;
    }
    #pragma unroll
    for (int o = 32; o > 0; o >>= 1) acc += __shfl_down(acc, o);
    if ((t & 63) == 0) red[t >> 6] = acc;
    __syncthreads();
    float svb = sqv[b];
    if (t == 0) t2[b] = svb * (red[0] + red[1] + red[2] + red[3]);
    if ((t >> 3) <= (b >> 3)) {  // lower blocks incl. intra-block upper
      int cj = ind[t];
      float rv = row[cj];
      Mp_g[blk_off(b >> 3, t >> 3) + (b & 7) * 8 + (t & 7)] =
          svb * sqv[t] * rv + ((t == b) ? 1.0f : 0.0f);
    }
  } else {
    const float4* z4 = (const float4*)z;
    const float4* S4 = (const float4*)S;
    float acc = 0.0f;
    #pragma unroll
    for (int m = 0; m < 8; ++m) {
      float4 a = z4[t + m * 256];
      float4 s = S4[t + m * 256];
      acc += a.x * s.x + a.y * s.y + a.z * s.z + a.w * s.w;
    }
    #pragma unroll
    for (int o = 32; o > 0; o >>= 1) acc += __shfl_down(acc, o);
    if ((t & 63) == 0) red[t >> 6] = acc;
    __syncthreads();
    if (t == 0) zS[0] = red[0] + red[1] + red[2] + red[3];
  }
}

// ---------------- K3: LDS-resident blocked Cholesky + MFMA SYRK + loss ------
__global__ __launch_bounds__(1024) void k_chol(
    const float* __restrict__ Mp_g, const float* __restrict__ t1w,
    const float* __restrict__ t2w, const float* __restrict__ kltw,
    const float* __restrict__ zSw, float* __restrict__ out) {
  __shared__ __align__(16) float Mp[PK_TOTAL];  // 143.6 KB packed lower
  __shared__ __align__(16) float Ld[32 * 36];
  __shared__ float rhs1[256], rhs2[256], dv[256];
  __shared__ float idv32[32], y1[32], y2[32];
  __shared__ float red[48];
  int t = threadIdx.x;

  // prologue: packed M -> LDS, rhs -> LDS
  {
    const float4* src = (const float4*)Mp_g;
    float4* dst = (float4*)Mp;
    for (int i = t; i < PK_TOTAL / 4; i += 1024) dst[i] = src[i];
  }
  if (t < 256) { rhs1[t] = t1w[t]; rhs2[t] = t2w[t]; }
  __syncthreads();

  for (int K = 0; K < 8; ++K) {
    int base = K * 32;
    int nb = 224 - base;  // trailing rows below this diag block
    // ---- phase1 (wave0): load diag rows, factor, solve RHS block ----
    if (t < 64) {
      if (t < 32) {
        int r = t;
        int I = (base >> 3) + (r >> 3);
        float a[32];
        #pragma unroll
        for (int cb = 0; cb < 4; ++cb) {
          float4 v0 = {0.f, 0.f, 0.f, 0.f}, v1 = {0.f, 0.f, 0.f, 0.f};
          if (cb <= (r >> 3)) {
            int o = blk_off(I, (base >> 3) + cb) + (r & 7) * 8;
            v0 = *(const float4*)&Mp[o];
            v1 = *(const float4*)&Mp[o + 4];
          }
          a[cb * 8 + 0] = v0.x; a[cb * 8 + 1] = v0.y;
          a[cb * 8 + 2] = v0.z; a[cb * 8 + 3] = v0.w;
          a[cb * 8 + 4] = v1.x; a[cb * 8 + 5] = v1.y;
          a[cb * 8 + 6] = v1.z; a[cb * 8 + 7] = v1.w;
        }
        float myrt = 1.0f, myrinv = 1.0f;
        #pragma unroll
        for (int k = 0; k < 32; ++k) {
          float d = bcast_lane(a[k], k);
          float rinv = rsqrtf(d);
          float rt = d * rinv;
          float m = (r == k) ? rt : a[k] * rinv;
          if (r == k) { myrt = rt; myrinv = rinv; }
          a[k] = m;
          #pragma unroll
          for (int c = k + 1; c < 32; ++c) {
            float lck = bcast_lane(m, c);
            if (r >= c) a[c] -= m * lck;
          }
        }
        #pragma unroll
        for (int c = 0; c < 32; ++c) Ld[r * 36 + c] = a[c];
        dv[base + r] = myrt;
        idv32[r] = myrinv;
      }
      __builtin_amdgcn_wave_barrier();
      asm volatile("s_waitcnt lgkmcnt(0)" ::: "memory");
      __builtin_amdgcn_sched_barrier(0);
      {  // B2: lanes 0..31 solve rhs1 block, 32..63 rhs2 block
        int r = t & 31;
        float v = (t < 32) ? rhs1[base + r] : rhs2[base + r];
        #pragma unroll
        for (int k = 0; k < 32; ++k) {
          float vk = __shfl(v, (t & 32) | k, 64);
          float yk = vk * idv32[k];
          if (r == k) v = yk;
          else if (r > k) v -= Ld[r * 36 + k] * yk;
        }
        if (t < 32) { rhs1[base + r] = v; y1[r] = v; }
        else        { rhs2[base + r] = v; y2[r] = v; }
      }
    }
    __syncthreads();
    // ---- phase2: TRSM panel rows in place + rhs trailing update ----
    if (nb > 0 && t < nb) {
      int gi = base + 32 + t;
      int I = gi >> 3, Jb = base >> 3;
      float a[32];
      #pragma unroll
      for (int cb = 0; cb < 4; ++cb) {
        int o = blk_off(I, Jb + cb) + (gi & 7) * 8;
        float4 v0 = *(const float4*)&Mp[o];
        float4 v1 = *(const float4*)&Mp[o + 4];
        a[cb * 8 + 0] = v0.x; a[cb * 8 + 1] = v0.y;
        a[cb * 8 + 2] = v0.z; a[cb * 8 + 3] = v0.w;
        a[cb * 8 + 4] = v1.x; a[cb * 8 + 5] = v1.y;
        a[cb * 8 + 6] = v1.z; a[cb * 8 + 7] = v1.w;
      }
      #pragma unroll
      for (int c = 0; c < 32; ++c) {
        float s = a[c];
        #pragma unroll
        for (int k = 0; k < c; ++k) s -= a[k] * Ld[c * 36 + k];
        a[c] = s * idv32[c];  // a[] becomes x[] in place
      }
      float s1 = 0.0f, s2 = 0.0f;
      #pragma unroll
      for (int k = 0; k < 32; ++k) { s1 += a[k] * y1[k]; s2 += a[k] * y2[k]; }
      rhs1[gi] -= s1;
      rhs2[gi] -= s2;
      #pragma unroll
      for (int cb = 0; cb < 4; ++cb) {
        int o = blk_off(I, Jb + cb) + (gi & 7) * 8;
        float4 w0 = {a[cb * 8 + 0], a[cb * 8 + 1], a[cb * 8 + 2], a[cb * 8 + 3]};
        float4 w1 = {a[cb * 8 + 4], a[cb * 8 + 5], a[cb * 8 + 6], a[cb * 8 + 7]};
        *(float4*)&Mp[o] = w0;
        *(float4*)&Mp[o + 4] = w1;
      }
    }
    __syncthreads();
    // ---- phase3: SYRK trailing update, one 32x32 tile per wave, MFMA ----
    if (nb > 0) {
      int nbb = nb >> 5;
      int ntiles = (nbb * (nbb + 1)) >> 1;
      int w = t >> 6, ln = t & 63;
      int lane31 = ln & 31, kh = ln >> 5;
      for (int idx = w; idx < ntiles; idx += 16) {
        int ti = 0;
        while ((((ti + 1) * (ti + 2)) >> 1) <= idx) ++ti;
        int tj = idx - ((ti * (ti + 1)) >> 1);
        int r_abs = base + 32 + ti * 32 + lane31;
        int c_abs = base + 32 + tj * 32 + lane31;
        f32x16 acc = {};
        #pragma unroll
        for (int k0 = 0; k0 < 2; ++k0) {
          int kb = base + k0 * 16 + kh * 8;
          short8_t ahi, alo, bhi, blo;
          frag_from_row(Mp, r_abs, kb, ahi, alo);
          frag_from_row(Mp, c_abs, kb, bhi, blo);
          acc = __builtin_amdgcn_mfma_f32_32x32x16_bf16(ahi, bhi, acc, 0, 0, 0);
          acc = __builtin_amdgcn_mfma_f32_32x32x16_bf16(ahi, blo, acc, 0, 0, 0);
          acc = __builtin_amdgcn_mfma_f32_32x32x16_bf16(alo, bhi, acc, 0, 0, 0);
        }
        int Rb = base + 32 + ti * 32;
        int Cc = base + 32 + tj * 32 + lane31;
        #pragma unroll
        for (int reg = 0; reg < 16; ++reg) {
          int Rr = Rb + (reg & 3) + 8 * (reg >> 2) + 4 * kh;
          if ((Cc >> 3) <= (Rr >> 3)) {
            int o = blk_off(Rr >> 3, Cc >> 3) + (Rr & 7) * 8 + (Cc & 7);
            Mp[o] -= acc[reg];
          }
        }
      }
    }
    __syncthreads();
  }

  // Epilogue: logdet/2 = sum log Lii ; q = w1.w2 ; kl ; final loss
  float v1 = 0.0f, v2 = 0.0f, v3 = 0.0f;
  if (t < 256) {
    v1 = logf(dv[t]);
    v2 = rhs1[t] * rhs2[t];
    v3 = kltw[t];
  }
  #pragma unroll
  for (int o = 32; o > 0; o >>= 1) {
    v1 += __shfl_down(v1, o);
    v2 += __shfl_down(v2, o);
    v3 += __shfl_down(v3, o);
  }
  if ((t & 63) == 0) {
    int w = t >> 6;
    red[w] = v1; red[16 + w] = v2; red[32 + w] = v3;
  }
  __syncthreads();
  if (t == 0) {
    float ld = 0.0f, q = 0.0f, kl = 0.0f;
    for (int w = 0; w < 16; ++w) {
      ld += red[w]; q += red[16 + w]; kl += red[32 + w];
    }
    out[0] = ld + 0.5f * (zSw[0] - q) + kl;
  }
}

extern "C" void kernel_launch(void* const* d_in, const int* in_sizes, int n_in,
                              void* d_out, int out_size, void* d_ws, size_t ws_size,
                              hipStream_t stream) {
  const float* R      = (const float*)d_in[0];
  const float* z      = (const float*)d_in[1];
  const float* sigma2 = (const float*)d_in[2];
  const float* p      = (const float*)d_in[3];
  const float* pq     = (const float*)d_in[4];
  const float* gamma  = (const float*)d_in[5];
  const float* S      = (const float*)d_in[6];
  const int*   Nptr   = (const int*)d_in[7];
  float* out = (float*)d_out;

  float* wsf  = (float*)d_ws;
  float* Mp_g = wsf;                         // PK_TOTAL floats (packed M)
  int*   ind  = (int*)(wsf + PK_TOTAL);      // 256
  float* sqv  = wsf + PK_TOTAL + 256;
  float* t1   = wsf + PK_TOTAL + 512;
  float* t2   = wsf + PK_TOTAL + 768;
  float* klt  = wsf + PK_TOTAL + 1024;
  float* zS   = wsf + PK_TOTAL + 1280;

  k_topk<<<256, 256, 0, stream>>>(gamma, sigma2, z, p, pq, Nptr,
                                  ind, sqv, t1, klt);
  k_vs<<<257, 256, 0, stream>>>(R, S, z, ind, sqv, Mp_g, t2, zS);
  k_chol<<<1, 1024, 0, stream>>>(Mp_g, t1, t2, klt, zS, out);
}

// Round 3
// 160.919 us; speedup vs baseline: 1.0519x; 1.0519x over previous
//
#include <hip/hip_runtime.h>
#include <cstdint>
#include <cstddef>

// ELBO loss: top-256 of gamma -> M = I + D^1/2 Rkk D^1/2 (SPD, packed lower
// 8x8-blocks in LDS) -> blocked Cholesky (NB=32) with MFMA split-bf16 SYRK
// -> loss = sum(log Lii) + 0.5*(z.S - (L^-1 t1).(L^-1 t2)) + KL
//
// Packed layout: element (i,j), j<=i: blk(I=i>>3, J=j>>3) at
// (I*(I+1)/2+J)*68 + (i&7)*8 + (j&7).  68-float block stride skews banks.
//
// R3 change: after TRSM of step K, panel cols [base,base+32) are dead ->
// phase2 splits x to bf16 hi/lo IN REGISTERS and overwrites each 8-float
// slot with [hi8|lo8] shorts. Phase3 frag build = 1 ds_read_b128 per frag
// (was 2 f32 reads + 64 VALU of split per frag, re-done per tile).

#define BLK_STRIDE 68
#define PK_TOTAL (528 * BLK_STRIDE)  // 35904 floats = 143616 B

typedef __attribute__((ext_vector_type(8))) short short8_t;
typedef __attribute__((ext_vector_type(16))) float f32x16;

__device__ __forceinline__ int blk_off(int I, int J) {
  return (((I * (I + 1)) >> 1) + J) * BLK_STRIDE;
}

__device__ __forceinline__ float bcast_lane(float v, int lane) {
  return __int_as_float(__builtin_amdgcn_readlane(__float_as_int(v), lane));
}

// RNE split: f ~= hi + lo in bf16 bit-patterns (as shorts)
__device__ __forceinline__ void split_bf16(float f, short& h, short& l) {
  unsigned u = __float_as_uint(f);
  unsigned hr = (u + 0x7FFFu + ((u >> 16) & 1u)) >> 16;
  h = (short)hr;
  float hf = __uint_as_float(hr << 16);
  float lf = f - hf;
  unsigned u2 = __float_as_uint(lf);
  l = (short)((u2 + 0x7FFFu + ((u2 >> 16) & 1u)) >> 16);
}

// ---------------- K1: exact top-256 select by rank + per-selected scalars ---
__global__ __launch_bounds__(256) void k_topk(
    const float* __restrict__ gamma, const float* __restrict__ sigma2,
    const float* __restrict__ z, const float* __restrict__ p,
    const float* __restrict__ pq, const int* __restrict__ Nptr,
    int* __restrict__ ind, float* __restrict__ sqv,
    float* __restrict__ t1, float* __restrict__ klt) {
  __shared__ __align__(16) float g[8 * 1032];
  int t = threadIdx.x;
  const float4* ga4 = (const float4*)gamma;
  #pragma unroll
  for (int m = 0; m < 8; ++m) {
    int i = 4 * (t + m * 256);
    float4 v = ga4[t + m * 256];
    *(float4*)&g[i + 8 * (i >> 10)] = v;
  }
  __syncthreads();
  int e = blockIdx.x * 32 + (t >> 3);
  int chunk = t & 7;
  float ge = g[e + 8 * (e >> 10)];
  const float4* g4 = (const float4*)g;
  int i4base = chunk * 258;
  int jbase = chunk * 1024;
  int cnt = 0;
  for (int it = 0; it < 256; ++it) {
    float4 v = g4[i4base + it];
    int j = jbase + 4 * it;
    cnt += (v.x > ge || (v.x == ge && (j + 0) < e)) ? 1 : 0;
    cnt += (v.y > ge || (v.y == ge && (j + 1) < e)) ? 1 : 0;
    cnt += (v.z > ge || (v.z == ge && (j + 2) < e)) ? 1 : 0;
    cnt += (v.w > ge || (v.w == ge && (j + 3) < e)) ? 1 : 0;
  }
  cnt += __shfl_xor(cnt, 1);
  cnt += __shfl_xor(cnt, 2);
  cnt += __shfl_xor(cnt, 4);
  if (chunk == 0 && cnt < 256) {
    float u = ge;
    float mask = (u > 0.01f) ? 1.0f : 0.0f;
    float fN = (float)Nptr[0];
    float vals = fN * sigma2[e] * u * mask;
    float sq = sqrtf(vals);
    ind[cnt] = e;
    sqv[cnt] = sq;
    t1[cnt] = sq * z[e];
    float x1 = p[e], x2 = pq[e];
    klt[cnt] = mask * (x2 * (logf(x2) - logf(x1)) +
                       (1.0f - x2) * (logf(1.0f - x2) - logf(1.0f - x1)));
  }
}

// ---------------- K2: VS = Rk.S, build packed M, and z.S --------------------
__global__ __launch_bounds__(256) void k_vs(
    const float* __restrict__ R, const float* __restrict__ S,
    const float* __restrict__ z, const int* __restrict__ ind,
    const float* __restrict__ sqv, float* __restrict__ Mp_g,
    float* __restrict__ t2, float* __restrict__ zS) {
  __shared__ __align__(16) float row[8192];
  __shared__ float red[4];
  int t = threadIdx.x;
  int b = blockIdx.x;
  if (b < 256) {
    int ridx = ind[b];
    const float4* Rr = (const float4*)(R + (size_t)ridx * 8192);
    const float4* S4 = (const float4*)S;
    float4* row4 = (float4*)row;
    float acc = 0.0f;
    #pragma unroll
    for (int m = 0; m < 8; ++m) {
      float4 v = Rr[t + m * 256];
      row4[t + m * 256] = v;
      float4 s = S4[t + m * 256];
      acc += v.x * s.x + v.y * s.y + v.z * s.z + v.w * s.w;
    }
    #pragma unroll
    for (int o = 32; o > 0; o >>= 1) acc += __shfl_down(acc, o);
    if ((t & 63) == 0) red[t >> 6] = acc;
    __syncthreads();
    float svb = sqv[b];
    if (t == 0) t2[b] = svb * (red[0] + red[1] + red[2] + red[3]);
    if ((t >> 3) <= (b >> 3)) {  // lower blocks incl. intra-block upper
      int cj = ind[t];
      float rv = row[cj];
      Mp_g[blk_off(b >> 3, t >> 3) + (b & 7) * 8 + (t & 7)] =
          svb * sqv[t] * rv + ((t == b) ? 1.0f : 0.0f);
    }
  } else {
    const float4* z4 = (const float4*)z;
    const float4* S4 = (const float4*)S;
    float acc = 0.0f;
    #pragma unroll
    for (int m = 0; m < 8; ++m) {
      float4 a = z4[t + m * 256];
      float4 s = S4[t + m * 256];
      acc += a.x * s.x + a.y * s.y + a.z * s.z + a.w * s.w;
    }
    #pragma unroll
    for (int o = 32; o > 0; o >>= 1) acc += __shfl_down(acc, o);
    if ((t & 63) == 0) red[t >> 6] = acc;
    __syncthreads();
    if (t == 0) zS[0] = red[0] + red[1] + red[2] + red[3];
  }
}

// ---------------- K3: LDS-resident blocked Cholesky + MFMA SYRK + loss ------
__global__ __launch_bounds__(1024) void k_chol(
    const float* __restrict__ Mp_g, const float* __restrict__ t1w,
    const float* __restrict__ t2w, const float* __restrict__ kltw,
    const float* __restrict__ zSw, float* __restrict__ out) {
  __shared__ __align__(16) float Mp[PK_TOTAL];  // 143.6 KB packed lower
  __shared__ __align__(16) float Ld[32 * 36];
  __shared__ float rhs1[256], rhs2[256], dv[256];
  __shared__ float idv32[32], y1[32], y2[32];
  __shared__ float red[48];
  int t = threadIdx.x;

  // prologue: packed M -> LDS, rhs -> LDS
  {
    const float4* src = (const float4*)Mp_g;
    float4* dst = (float4*)Mp;
    for (int i = t; i < PK_TOTAL / 4; i += 1024) dst[i] = src[i];
  }
  if (t < 256) { rhs1[t] = t1w[t]; rhs2[t] = t2w[t]; }
  __syncthreads();

  for (int K = 0; K < 8; ++K) {
    int base = K * 32;
    int nb = 224 - base;  // trailing rows below this diag block
    // ---- phase1 (wave0): load diag rows, factor, solve RHS block ----
    if (t < 64) {
      if (t < 32) {
        int r = t;
        int I = (base >> 3) + (r >> 3);
        float a[32];
        #pragma unroll
        for (int cb = 0; cb < 4; ++cb) {
          float4 v0 = {0.f, 0.f, 0.f, 0.f}, v1 = {0.f, 0.f, 0.f, 0.f};
          if (cb <= (r >> 3)) {
            int o = blk_off(I, (base >> 3) + cb) + (r & 7) * 8;
            v0 = *(const float4*)&Mp[o];
            v1 = *(const float4*)&Mp[o + 4];
          }
          a[cb * 8 + 0] = v0.x; a[cb * 8 + 1] = v0.y;
          a[cb * 8 + 2] = v0.z; a[cb * 8 + 3] = v0.w;
          a[cb * 8 + 4] = v1.x; a[cb * 8 + 5] = v1.y;
          a[cb * 8 + 6] = v1.z; a[cb * 8 + 7] = v1.w;
        }
        float myrt = 1.0f, myrinv = 1.0f;
        #pragma unroll
        for (int k = 0; k < 32; ++k) {
          float d = bcast_lane(a[k], k);
          float rinv = rsqrtf(d);
          float rt = d * rinv;
          float m = (r == k) ? rt : a[k] * rinv;
          if (r == k) { myrt = rt; myrinv = rinv; }
          a[k] = m;
          #pragma unroll
          for (int c = k + 1; c < 32; ++c) {
            float lck = bcast_lane(m, c);
            if (r >= c) a[c] -= m * lck;
          }
        }
        #pragma unroll
        for (int c = 0; c < 32; ++c) Ld[r * 36 + c] = a[c];
        dv[base + r] = myrt;
        idv32[r] = myrinv;
      }
      __builtin_amdgcn_wave_barrier();
      asm volatile("s_waitcnt lgkmcnt(0)" ::: "memory");
      __builtin_amdgcn_sched_barrier(0);
      {  // B2: lanes 0..31 solve rhs1 block, 32..63 rhs2 block
        int r = t & 31;
        float v = (t < 32) ? rhs1[base + r] : rhs2[base + r];
        #pragma unroll
        for (int k = 0; k < 32; ++k) {
          float vk = __shfl(v, (t & 32) | k, 64);
          float yk = vk * idv32[k];
          if (r == k) v = yk;
          else if (r > k) v -= Ld[r * 36 + k] * yk;
        }
        if (t < 32) { rhs1[base + r] = v; y1[r] = v; }
        else        { rhs2[base + r] = v; y2[r] = v; }
      }
    }
    __syncthreads();
    // ---- phase2: TRSM panel rows in place + rhs update + bf16 split-store --
    if (nb > 0 && t < nb) {
      int gi = base + 32 + t;
      int I = gi >> 3, Jb = base >> 3;
      float a[32];
      #pragma unroll
      for (int cb = 0; cb < 4; ++cb) {
        int o = blk_off(I, Jb + cb) + (gi & 7) * 8;
        float4 v0 = *(const float4*)&Mp[o];
        float4 v1 = *(const float4*)&Mp[o + 4];
        a[cb * 8 + 0] = v0.x; a[cb * 8 + 1] = v0.y;
        a[cb * 8 + 2] = v0.z; a[cb * 8 + 3] = v0.w;
        a[cb * 8 + 4] = v1.x; a[cb * 8 + 5] = v1.y;
        a[cb * 8 + 6] = v1.z; a[cb * 8 + 7] = v1.w;
      }
      #pragma unroll
      for (int c = 0; c < 32; ++c) {
        float s = a[c];
        #pragma unroll
        for (int k = 0; k < c; ++k) s -= a[k] * Ld[c * 36 + k];
        a[c] = s * idv32[c];  // a[] becomes x[] in place
      }
      float s1 = 0.0f, s2 = 0.0f;
      #pragma unroll
      for (int k = 0; k < 32; ++k) { s1 += a[k] * y1[k]; s2 += a[k] * y2[k]; }
      rhs1[gi] -= s1;
      rhs2[gi] -= s2;
      // overwrite dead f32 panel slots with [hi8|lo8] bf16 split (32B each)
      #pragma unroll
      for (int cb = 0; cb < 4; ++cb) {
        int o = blk_off(I, Jb + cb) + (gi & 7) * 8;
        short8_t h8, l8;
        #pragma unroll
        for (int e = 0; e < 8; ++e) {
          short hh, ll;
          split_bf16(a[cb * 8 + e], hh, ll);
          h8[e] = hh;
          l8[e] = ll;
        }
        *(short8_t*)&Mp[o] = h8;
        *(short8_t*)&Mp[o + 4] = l8;
      }
    }
    __syncthreads();
    // ---- phase3: SYRK trailing update, one 32x32 tile per wave, MFMA ----
    if (nb > 0) {
      int nbb = nb >> 5;
      int ntiles = (nbb * (nbb + 1)) >> 1;
      int w = t >> 6, ln = t & 63;
      int lane31 = ln & 31, kh = ln >> 5;
      for (int idx = w; idx < ntiles; idx += 16) {
        int ti = 0;
        while ((((ti + 1) * (ti + 2)) >> 1) <= idx) ++ti;
        int tj = idx - ((ti * (ti + 1)) >> 1);
        int r_abs = base + 32 + ti * 32 + lane31;
        int c_abs = base + 32 + tj * 32 + lane31;
        f32x16 acc = {};
        #pragma unroll
        for (int k0 = 0; k0 < 2; ++k0) {
          int kb = base + k0 * 16 + kh * 8;
          int oa = blk_off(r_abs >> 3, kb >> 3) + (r_abs & 7) * 8;
          int ob = blk_off(c_abs >> 3, kb >> 3) + (c_abs & 7) * 8;
          short8_t ahi = *(const short8_t*)&Mp[oa];
          short8_t alo = *(const short8_t*)&Mp[oa + 4];
          short8_t bhi = *(const short8_t*)&Mp[ob];
          short8_t blo = *(const short8_t*)&Mp[ob + 4];
          acc = __builtin_amdgcn_mfma_f32_32x32x16_bf16(ahi, bhi, acc, 0, 0, 0);
          acc = __builtin_amdgcn_mfma_f32_32x32x16_bf16(ahi, blo, acc, 0, 0, 0);
          acc = __builtin_amdgcn_mfma_f32_32x32x16_bf16(alo, bhi, acc, 0, 0, 0);
        }
        int Rb = base + 32 + ti * 32;
        int Cc = base + 32 + tj * 32 + lane31;
        #pragma unroll
        for (int reg = 0; reg < 16; ++reg) {
          int Rr = Rb + (reg & 3) + 8 * (reg >> 2) + 4 * kh;
          if ((Cc >> 3) <= (Rr >> 3)) {
            int o = blk_off(Rr >> 3, Cc >> 3) + (Rr & 7) * 8 + (Cc & 7);
            Mp[o] -= acc[reg];
          }
        }
      }
    }
    __syncthreads();
  }

  // Epilogue: logdet/2 = sum log Lii ; q = w1.w2 ; kl ; final loss
  float v1 = 0.0f, v2 = 0.0f, v3 = 0.0f;
  if (t < 256) {
    v1 = logf(dv[t]);
    v2 = rhs1[t] * rhs2[t];
    v3 = kltw[t];
  }
  #pragma unroll
  for (int o = 32; o > 0; o >>= 1) {
    v1 += __shfl_down(v1, o);
    v2 += __shfl_down(v2, o);
    v3 += __shfl_down(v3, o);
  }
  if ((t & 63) == 0) {
    int w = t >> 6;
    red[w] = v1; red[16 + w] = v2; red[32 + w] = v3;
  }
  __syncthreads();
  if (t == 0) {
    float ld = 0.0f, q = 0.0f, kl = 0.0f;
    for (int w = 0; w < 16; ++w) {
      ld += red[w]; q += red[16 + w]; kl += red[32 + w];
    }
    out[0] = ld + 0.5f * (zSw[0] - q) + kl;
  }
}

extern "C" void kernel_launch(void* const* d_in, const int* in_sizes, int n_in,
                              void* d_out, int out_size, void* d_ws, size_t ws_size,
                              hipStream_t stream) {
  const float* R      = (const float*)d_in[0];
  const float* z      = (const float*)d_in[1];
  const float* sigma2 = (const float*)d_in[2];
  const float* p      = (const float*)d_in[3];
  const float* pq     = (const float*)d_in[4];
  const float* gamma  = (const float*)d_in[5];
  const float* S      = (const float*)d_in[6];
  const int*   Nptr   = (const int*)d_in[7];
  float* out = (float*)d_out;

  float* wsf  = (float*)d_ws;
  float* Mp_g = wsf;                         // PK_TOTAL floats (packed M)
  int*   ind  = (int*)(wsf + PK_TOTAL);      // 256
  float* sqv  = wsf + PK_TOTAL + 256;
  float* t1   = wsf + PK_TOTAL + 512;
  float* t2   = wsf + PK_TOTAL + 768;
  float* klt  = wsf + PK_TOTAL + 1024;
  float* zS   = wsf + PK_TOTAL + 1280;

  k_topk<<<256, 256, 0, stream>>>(gamma, sigma2, z, p, pq, Nptr,
                                  ind, sqv, t1, klt);
  k_vs<<<257, 256, 0, stream>>>(R, S, z, ind, sqv, Mp_g, t2, zS);
  k_chol<<<1, 1024, 0, stream>>>(Mp_g, t1, t2, klt, zS, out);
}